// Round 14
// baseline (576.597 us; speedup 1.0000x reference)
//
#include <hip/hip_runtime.h>
#include <hip/hip_bf16.h>

#define NN 20000      // nodes
#define NE 320000     // edges
#define NG 64         // graphs
#define HEADS 4
#define CD 32         // dim per head
#define HC 128        // HEADS*CD
#define ED 16         // edge feature dim

typedef unsigned short ushort_t;
typedef float v2f __attribute__((ext_vector_type(2)));
typedef float v4f __attribute__((ext_vector_type(4)));

__device__ __forceinline__ float bf2f(unsigned u16) {
    return __uint_as_float(u16 << 16);
}
__device__ __forceinline__ unsigned short f2bf(float f) {
    unsigned u = __float_as_uint(f);
    return (unsigned short)((u + 0x7FFFu + ((u >> 16) & 1u)) >> 16);
}

// ---- node GEMM: out = x @ W, W selected by blockIdx.y ----
// sel 0 -> q (f32) + fused qwe; sel 1 -> k into kv (fp8, off 0); sel 2 -> v (off 4)
// Streaming data (x read, q/qwe writes) is nontemporal; W stays cached.
__global__ __launch_bounds__(256) void k_qkv(const float* __restrict__ xin,
        const float* __restrict__ Wq, const float* __restrict__ Wk,
        const float* __restrict__ Wv, const float* __restrict__ We,
        float* __restrict__ qo, unsigned char* __restrict__ kv,
        float* __restrict__ qwe) {
    __shared__ float xs[32 * HC];   // 16 KB (x tile, then reused as q tile)
    const int t = threadIdx.x;
    const int n0 = blockIdx.x * 32;
    const int sel = blockIdx.y;
    const float* __restrict__ W = (sel == 0) ? Wq : (sel == 1) ? Wk : Wv;
    {
        const v4f* src = (const v4f*)(xin + (size_t)n0 * HC);
        v4f* dst = (v4f*)xs;
        #pragma unroll
        for (int i = 0; i < 4; ++i)
            dst[t + 256 * i] = __builtin_nontemporal_load(src + t + 256 * i);
    }
    __syncthreads();
    const int tx = t & 31, ty = t >> 5;
    const int c0 = tx * 4, m0 = ty * 4;
    float acc[4][4];
    #pragma unroll
    for (int im = 0; im < 4; ++im)
        #pragma unroll
        for (int c = 0; c < 4; ++c) acc[im][c] = 0.f;

    #pragma unroll 2
    for (int kk = 0; kk < HC; kk += 4) {
        float xfrag[4][4];
        #pragma unroll
        for (int im = 0; im < 4; ++im) {
            float4 xf = *(const float4*)&xs[(m0 + im) * HC + kk];
            xfrag[im][0] = xf.x; xfrag[im][1] = xf.y;
            xfrag[im][2] = xf.z; xfrag[im][3] = xf.w;
        }
        #pragma unroll
        for (int r = 0; r < 4; ++r) {
            float4 w = *(const float4*)&W[(size_t)(kk + r) * HC + c0];
            #pragma unroll
            for (int im = 0; im < 4; ++im) {
                float xv = xfrag[im][r];
                acc[im][0] += xv * w.x; acc[im][1] += xv * w.y;
                acc[im][2] += xv * w.z; acc[im][3] += xv * w.w;
            }
        }
    }
    #pragma unroll
    for (int im = 0; im < 4; ++im) {
        const size_t n = (size_t)(n0 + m0 + im);
        if (sel == 0) {
            v4f qv = {acc[im][0], acc[im][1], acc[im][2], acc[im][3]};
            __builtin_nontemporal_store(qv, (v4f*)&qo[n * HC + c0]);
        } else {
            unsigned d = 0;
            d = __builtin_amdgcn_cvt_pk_fp8_f32(acc[im][0], acc[im][1], d, false);
            d = __builtin_amdgcn_cvt_pk_fp8_f32(acc[im][2], acc[im][3], d, true);
            *(unsigned*)&kv[n * 256 + tx * 8 + ((sel == 1) ? 0 : 4)] = d;
        }
    }
    if (sel == 0) {
        // fused qwe: stage q tile back into xs, then each thread computes 8
        // qwe entries for one node. qwe[n, h*16+j] = sum_c q[n,h*32+c]*We[j,h*32+c]
        __syncthreads();
        #pragma unroll
        for (int im = 0; im < 4; ++im)
            *(float4*)&xs[(m0 + im) * HC + c0] =
                make_float4(acc[im][0], acc[im][1], acc[im][2], acc[im][3]);
        __syncthreads();
        const int nl = t >> 3;            // node 0..31
        const int e0i = (t & 7) * 8;      // entry 0..56
        float res[8];
        #pragma unroll
        for (int e = 0; e < 8; ++e) {
            const int idx = e0i + e;
            const int h = idx >> 4, j = idx & 15;
            const float* qrow = &xs[nl * HC + h * 32];
            const float* wrow = &We[(size_t)j * HC + h * 32];
            float s = 0.f;
            #pragma unroll
            for (int c = 0; c < 32; c += 4) {
                float4 qf = *(const float4*)&qrow[c];
                float4 wf = *(const float4*)&wrow[c];
                s += qf.x * wf.x + qf.y * wf.y + qf.z * wf.z + qf.w * wf.w;
            }
            res[e] = s;
        }
        float* qd = &qwe[(size_t)(n0 + nl) * 64 + e0i];
        v4f r0 = {res[0], res[1], res[2], res[3]};
        v4f r1 = {res[4], res[5], res[6], res[7]};
        __builtin_nontemporal_store(r0, (v4f*)&qd[0]);
        __builtin_nontemporal_store(r1, (v4f*)&qd[4]);
    }
}

// ---- CSR build: deg histogram only (int atomics, cheap) ----
__global__ void k_hist(const int* __restrict__ ei, int* __restrict__ deg) {
    int i = blockIdx.x * blockDim.x + threadIdx.x;
    if (i < NE) atomicAdd(&deg[ei[NE + i]], 1);
}

__global__ __launch_bounds__(1024) void k_scan(const int* __restrict__ deg,
        int* __restrict__ rowptr, int* __restrict__ nextp) {
    __shared__ int part[1024];
    const int t = threadIdx.x;
    const int b0 = t * 20;
    const int b1 = min(b0 + 20, NN);
    int s = 0;
    for (int i = b0; i < b1; ++i) s += deg[i];
    part[t] = s;
    __syncthreads();
    for (int off = 1; off < 1024; off <<= 1) {
        int val = (t >= off) ? part[t - off] : 0;
        __syncthreads();
        part[t] += val;
        __syncthreads();
    }
    int run = (t == 0) ? 0 : part[t - 1];
    for (int i = b0; i < b1; ++i) {
        rowptr[i] = run;
        nextp[i] = run;
        run += deg[i];
    }
    if (b1 == NN) rowptr[NN] = run;
}

// ---- scatter: esrc + ea pre-gathered to CSR order (bf16) ----
__global__ void k_scatter(const int* __restrict__ ei, int* __restrict__ nextp,
        int* __restrict__ esrc, ushort_t* __restrict__ eacsr,
        const float* __restrict__ ea) {
    int i = blockIdx.x * blockDim.x + threadIdx.x;
    if (i < NE) {
        int d = ei[NE + i];
        int pos = atomicAdd(&nextp[d], 1);
        esrc[pos] = ei[i];
        const v4f* s = (const v4f*)&ea[(size_t)i * ED];
        ushort_t* dst = eacsr + (size_t)pos * ED;
        #pragma unroll
        for (int r = 0; r < 4; ++r) {
            v4f f = __builtin_nontemporal_load(s + r);
            ushort4 u;
            u.x = f2bf(f.x); u.y = f2bf(f.y); u.z = f2bf(f.z); u.w = f2bf(f.w);
            *(ushort4*)&dst[r * 4] = u;
        }
    }
}

// ---- fused conv: one wave per dst node; 2 edges/iter, DEPTH-2 pipeline ----
// lane: g = lane>>5 (edge slot), j = lane&31 (cols j*4..+3), h = j>>3, w8 = j&7
// kv rows fp8 e4m3, 256B/row. kv loads CACHED (the only reused structure);
// all streaming loads (q, qwe, esrc, eacsr) and hout writes are nontemporal
// so L2 stays reserved for kv.
__global__ __launch_bounds__(256) void k_conv(
        const float* __restrict__ q, const unsigned char* __restrict__ kv,
        const ushort_t* __restrict__ eacsr,
        const float* __restrict__ qwe, const float* __restrict__ We,
        const int* __restrict__ rowptr, const int* __restrict__ esrc,
        const int* __restrict__ batch,
        float* __restrict__ hout, float* __restrict__ gsum, int mode) {
    const int wid = (blockIdx.x * blockDim.x + threadIdx.x) >> 6;
    if (wid >= NN) return;
    const int lane = threadIdx.x & 63;
    const int g = lane >> 5;
    const int j = lane & 31;
    const int c0 = j * 4;
    const int h = j >> 3;
    const int w8 = j & 7;
    const int beg = rowptr[wid];
    const int end = rowptr[wid + 1];
    const v4f qq = __builtin_nontemporal_load((const v4f*)&q[(size_t)wid * HC + c0]);
    const v2f qw2 = __builtin_nontemporal_load((const v2f*)&qwe[(size_t)wid * 64 + h * 16 + w8 * 2]);
    float4 av = make_float4(0.f, 0.f, 0.f, 0.f);
    float2 s2 = make_float2(0.f, 0.f);
    float den = 0.f;

    if (end > beg) {
        const int last = end - 1;
        int s0i = __builtin_nontemporal_load(&esrc[min(beg + g, last)]);
        int s1i = __builtin_nontemporal_load(&esrc[min(beg + 2 + g, last)]);
        int srcA = __builtin_nontemporal_load(&esrc[min(beg + 4 + g, last)]);
        int srcB = __builtin_nontemporal_load(&esrc[min(beg + 6 + g, last)]);
        uint2 kv0 = *(const uint2*)&kv[(size_t)s0i * 256 + j * 8];
        unsigned ea0 = __builtin_nontemporal_load((const unsigned*)&eacsr[(size_t)min(beg + g, last) * ED + w8 * 2]);
        uint2 kv1 = *(const uint2*)&kv[(size_t)s1i * 256 + j * 8];
        unsigned ea1 = __builtin_nontemporal_load((const unsigned*)&eacsr[(size_t)min(beg + 2 + g, last) * ED + w8 * 2]);
        bool act0 = (beg + g) < end;
        bool act1 = (beg + 2 + g) < end;
        const int niter = (end - beg + 1) >> 1;
        for (int i = 0; i < niter; ++i) {
            int srcN = __builtin_nontemporal_load(&esrc[min(beg + 2 * (i + 4) + g, last)]);
            uint2 kv2 = *(const uint2*)&kv[(size_t)srcA * 256 + j * 8];
            unsigned ea2 = __builtin_nontemporal_load((const unsigned*)&eacsr[(size_t)min(beg + 2 * (i + 2) + g, last) * ED + w8 * 2]);
            bool act2 = (beg + 2 * (i + 2) + g) < end;
            v2f k01 = __builtin_amdgcn_cvt_pk_f32_fp8(kv0.x, false);
            v2f k23 = __builtin_amdgcn_cvt_pk_f32_fp8(kv0.x, true);
            v2f v01 = __builtin_amdgcn_cvt_pk_f32_fp8(kv0.y, false);
            v2f v23 = __builtin_amdgcn_cvt_pk_f32_fp8(kv0.y, true);
            float e0 = bf2f(ea0 & 0xffffu), e1 = bf2f(ea0 >> 16);
            float part = qq.x * k01.x + qq.y * k01.y + qq.z * k23.x + qq.w * k23.y
                       + qw2.x * e0 + qw2.y * e1;
            part += __shfl_xor(part, 1);
            part += __shfl_xor(part, 2);
            part += __shfl_xor(part, 4);   // per-head logit (8 lanes/head)
            float p = act0 ? __expf(part * 0.17677669529663687f) : 0.f;
            den += p;
            av.x += p * v01.x; av.y += p * v01.y;
            av.z += p * v23.x; av.w += p * v23.y;
            s2.x += p * e0; s2.y += p * e1;
            kv0 = kv1; ea0 = ea1; act0 = act1;
            kv1 = kv2; ea1 = ea2; act1 = act2;
            srcA = srcB; srcB = srcN;
        }
    }
    den  += __shfl_xor(den, 32);
    av.x += __shfl_xor(av.x, 32); av.y += __shfl_xor(av.y, 32);
    av.z += __shfl_xor(av.z, 32); av.w += __shfl_xor(av.w, 32);
    s2.x += __shfl_xor(s2.x, 32); s2.y += __shfl_xor(s2.y, 32);
    const float inv = 1.f / (den + 1e-16f);
    float4 ew = make_float4(0.f, 0.f, 0.f, 0.f);
    #pragma unroll
    for (int t = 0; t < 8; ++t) {
        float sva = __shfl(s2.x, h * 8 + t, 32);
        float svb = __shfl(s2.y, h * 8 + t, 32);
        float4 wa = *(const float4*)&We[(2 * t) * HC + c0];
        float4 wb = *(const float4*)&We[(2 * t + 1) * HC + c0];
        ew.x += sva * wa.x + svb * wb.x;
        ew.y += sva * wa.y + svb * wb.y;
        ew.z += sva * wa.z + svb * wb.z;
        ew.w += sva * wa.w + svb * wb.w;
    }
    float o[4];
    o[0] = (av.x + ew.x) * inv; o[1] = (av.y + ew.y) * inv;
    o[2] = (av.z + ew.z) * inv; o[3] = (av.w + ew.w) * inv;

    const int b = batch[wid];
    if (mode == 0) {
        #pragma unroll
        for (int c = 0; c < 4; ++c) o[c] = fmaxf(o[c], 0.f);
        if (g == 0) {
            v4f ov = {o[0], o[1], o[2], o[3]};
            __builtin_nontemporal_store(ov, (v4f*)&hout[(size_t)wid * HC + c0]);
        }
    }
    #pragma unroll
    for (int c = 0; c < 4; ++c) {
        o[c] += __shfl_xor(o[c], 8);
        o[c] += __shfl_xor(o[c], 16);
    }
    if (lane < 8) {
        #pragma unroll
        for (int c = 0; c < 4; ++c) {
            float pv = 0.25f * o[c];
            if (mode == 1) pv = fmaxf(pv, 0.f);
            atomicAdd(&gsum[b * CD + w8 * 4 + c], pv);
        }
    }
}

// ---- final MLP + log_softmax: one block per graph ----
__global__ __launch_bounds__(128) void k_final(
        const float* __restrict__ gsum, const int* __restrict__ batch,
        const float* __restrict__ W1, const float* __restrict__ b1,
        const float* __restrict__ W2, const float* __restrict__ b2,
        float* __restrict__ out) {
    __shared__ float G[96];
    __shared__ float Y[96];
    __shared__ float Z[10];
    __shared__ int bnd[2];
    const int g = blockIdx.x;
    const int t = threadIdx.x;
    if (t < 2) {
        const int target = g + t;
        int lo = 0, hi = NN;
        while (lo < hi) {
            int mid = (lo + hi) >> 1;
            if (batch[mid] < target) lo = mid + 1; else hi = mid;
        }
        bnd[t] = lo;
    }
    __syncthreads();
    const float cn = fmaxf((float)(bnd[1] - bnd[0]), 1.f);
    if (t < 96) {
        int layer = t / 32, c = t % 32;
        G[t] = gsum[layer * NG * CD + g * CD + c] / cn;
    }
    __syncthreads();
    if (t < 96) {
        float s = b1[t];
        #pragma unroll 4
        for (int d = 0; d < 96; ++d) s += G[d] * W1[d * 96 + t];
        Y[t] = fmaxf(s, 0.f);
    }
    __syncthreads();
    if (t < 10) {
        float s = b2[t];
        #pragma unroll 4
        for (int d = 0; d < 96; ++d) s += Y[d] * W2[d * 10 + t];
        Z[t] = s;
    }
    __syncthreads();
    if (t < 10) {
        float mx = Z[0];
        #pragma unroll
        for (int o = 1; o < 10; ++o) mx = fmaxf(mx, Z[o]);
        float se = 0.f;
        #pragma unroll
        for (int o = 0; o < 10; ++o) se += expf(Z[o] - mx);
        out[g * 10 + t] = Z[t] - (mx + logf(se));
    }
}

extern "C" void kernel_launch(void* const* d_in, const int* in_sizes, int n_in,
                              void* d_out, int out_size, void* d_ws, size_t ws_size,
                              hipStream_t stream) {
    const float* x        = (const float*)d_in[0];
    const float* ea       = (const float*)d_in[1];
    const int*   ei       = (const int*)d_in[2];
    const int*   batch    = (const int*)d_in[3];
    const float* Wq[3] = {(const float*)d_in[4],  (const float*)d_in[8],  (const float*)d_in[12]};
    const float* Wk[3] = {(const float*)d_in[5],  (const float*)d_in[9],  (const float*)d_in[13]};
    const float* Wv[3] = {(const float*)d_in[6],  (const float*)d_in[10], (const float*)d_in[14]};
    const float* We[3] = {(const float*)d_in[7],  (const float*)d_in[11], (const float*)d_in[15]};
    const float* W1 = (const float*)d_in[16];
    const float* b1 = (const float*)d_in[17];
    const float* W2 = (const float*)d_in[18];
    const float* b2 = (const float*)d_in[19];
    float* out = (float*)d_out;

    // workspace layout (all 16B-aligned chunks)
    float* ws = (float*)d_ws;
    float* q      = ws;                      // NN*HC f32
    float* h1     = q + (size_t)NN * HC;     // NN*HC f32
    float* h2     = h1 + (size_t)NN * HC;    // NN*HC f32
    float* qwe    = h2 + (size_t)NN * HC;    // NN*64 f32
    float* gsum   = qwe + (size_t)NN * 64;   // 3*NG*CD
    int* deg      = (int*)(gsum + 3 * NG * CD);  // NN
    int* rowptr   = deg + NN;                // NN+2
    int* nextp    = rowptr + NN + 2;         // NN
    int* esrc     = nextp + NN;              // NE
    unsigned char* kv = (unsigned char*)(esrc + NE);   // NN*256 fp8 bytes
    ushort_t* eacsr = (ushort_t*)(kv + (size_t)NN * 256);  // NE*ED bf16

    hipMemsetAsync(gsum, 0, (3 * NG * CD) * sizeof(float), stream);
    hipMemsetAsync(deg, 0, NN * sizeof(int), stream);

    // CSR build (edge_index shared by all layers)
    k_hist<<<(NE + 255) / 256, 256, 0, stream>>>(ei, deg);
    k_scan<<<1, 1024, 0, stream>>>(deg, rowptr, nextp);
    k_scatter<<<(NE + 255) / 256, 256, 0, stream>>>(ei, nextp, esrc, eacsr, ea);

    const float* conv_in[3] = {x, h1, h2};
    float* conv_out[3] = {h1, h2, nullptr};
    const int CONV_BLOCKS = (NN * 64) / 256;   // one wave per node, 4 waves/block

    for (int l = 0; l < 3; ++l) {
        k_qkv<<<dim3(NN / 32, 3), 256, 0, stream>>>(conv_in[l], Wq[l], Wk[l], Wv[l],
                                                    We[l], q, kv, qwe);
        k_conv<<<CONV_BLOCKS, 256, 0, stream>>>(q, kv, eacsr, qwe, We[l],
                rowptr, esrc, batch,
                conv_out[l], gsum + l * NG * CD, (l < 2) ? 0 : 1);
    }
    k_final<<<NG, 128, 0, stream>>>(gsum, batch, W1, b1, W2, b2, out);
}

// Round 15
// 538.623 us; speedup vs baseline: 1.0705x; 1.0705x over previous
//
#include <hip/hip_runtime.h>
#include <hip/hip_bf16.h>

#define NN 20000      // nodes
#define NE 320000     // edges
#define NG 64         // graphs
#define HEADS 4
#define CD 32         // dim per head
#define HC 128        // HEADS*CD
#define ED 16         // edge feature dim

typedef unsigned short ushort_t;
typedef float v2f __attribute__((ext_vector_type(2)));

__device__ __forceinline__ float bf2f(unsigned u16) {
    return __uint_as_float(u16 << 16);
}
__device__ __forceinline__ unsigned short f2bf(float f) {
    unsigned u = __float_as_uint(f);
    return (unsigned short)((u + 0x7FFFu + ((u >> 16) & 1u)) >> 16);
}

// ---- node GEMM: out = x @ W, W selected by blockIdx.y ----
// sel 0 -> q (f32) + fused qwe; sel 1 -> k into kv (fp8, off 0); sel 2 -> v (off 4)
__global__ __launch_bounds__(256) void k_qkv(const float* __restrict__ xin,
        const float* __restrict__ Wq, const float* __restrict__ Wk,
        const float* __restrict__ Wv, const float* __restrict__ We,
        float* __restrict__ qo, unsigned char* __restrict__ kv,
        float* __restrict__ qwe) {
    __shared__ float xs[32 * HC];   // 16 KB (x tile, then reused as q tile)
    const int t = threadIdx.x;
    const int n0 = blockIdx.x * 32;
    const int sel = blockIdx.y;
    const float* __restrict__ W = (sel == 0) ? Wq : (sel == 1) ? Wk : Wv;
    {
        const float4* src = (const float4*)(xin + (size_t)n0 * HC);
        float4* dst = (float4*)xs;
        #pragma unroll
        for (int i = 0; i < 4; ++i)
            dst[t + 256 * i] = src[t + 256 * i];
    }
    __syncthreads();
    const int tx = t & 31, ty = t >> 5;
    const int c0 = tx * 4, m0 = ty * 4;
    float acc[4][4];
    #pragma unroll
    for (int im = 0; im < 4; ++im)
        #pragma unroll
        for (int c = 0; c < 4; ++c) acc[im][c] = 0.f;

    #pragma unroll 2
    for (int kk = 0; kk < HC; kk += 4) {
        float xfrag[4][4];
        #pragma unroll
        for (int im = 0; im < 4; ++im) {
            float4 xf = *(const float4*)&xs[(m0 + im) * HC + kk];
            xfrag[im][0] = xf.x; xfrag[im][1] = xf.y;
            xfrag[im][2] = xf.z; xfrag[im][3] = xf.w;
        }
        #pragma unroll
        for (int r = 0; r < 4; ++r) {
            float4 w = *(const float4*)&W[(size_t)(kk + r) * HC + c0];
            #pragma unroll
            for (int im = 0; im < 4; ++im) {
                float xv = xfrag[im][r];
                acc[im][0] += xv * w.x; acc[im][1] += xv * w.y;
                acc[im][2] += xv * w.z; acc[im][3] += xv * w.w;
            }
        }
    }
    #pragma unroll
    for (int im = 0; im < 4; ++im) {
        const size_t n = (size_t)(n0 + m0 + im);
        if (sel == 0) {
            *(float4*)&qo[n * HC + c0] =
                make_float4(acc[im][0], acc[im][1], acc[im][2], acc[im][3]);
        } else {
            unsigned d = 0;
            d = __builtin_amdgcn_cvt_pk_fp8_f32(acc[im][0], acc[im][1], d, false);
            d = __builtin_amdgcn_cvt_pk_fp8_f32(acc[im][2], acc[im][3], d, true);
            *(unsigned*)&kv[n * 256 + tx * 8 + ((sel == 1) ? 0 : 4)] = d;
        }
    }
    if (sel == 0) {
        // fused qwe: stage q tile back into xs, then each thread computes 8
        // qwe entries for one node. qwe[n, h*16+j] = sum_c q[n,h*32+c]*We[j,h*32+c]
        __syncthreads();
        #pragma unroll
        for (int im = 0; im < 4; ++im)
            *(float4*)&xs[(m0 + im) * HC + c0] =
                make_float4(acc[im][0], acc[im][1], acc[im][2], acc[im][3]);
        __syncthreads();
        const int nl = t >> 3;            // node 0..31
        const int e0i = (t & 7) * 8;      // entry 0..56
        float res[8];
        #pragma unroll
        for (int e = 0; e < 8; ++e) {
            const int idx = e0i + e;
            const int h = idx >> 4, j = idx & 15;
            const float* qrow = &xs[nl * HC + h * 32];
            const float* wrow = &We[(size_t)j * HC + h * 32];
            float s = 0.f;
            #pragma unroll
            for (int c = 0; c < 32; c += 4) {
                float4 qf = *(const float4*)&qrow[c];
                float4 wf = *(const float4*)&wrow[c];
                s += qf.x * wf.x + qf.y * wf.y + qf.z * wf.z + qf.w * wf.w;
            }
            res[e] = s;
        }
        float* qd = &qwe[(size_t)(n0 + nl) * 64 + e0i];
        *(float4*)&qd[0] = make_float4(res[0], res[1], res[2], res[3]);
        *(float4*)&qd[4] = make_float4(res[4], res[5], res[6], res[7]);
    }
}

// ---- CSR build: deg histogram only (int atomics, cheap) ----
__global__ void k_hist(const int* __restrict__ ei, int* __restrict__ deg) {
    int i = blockIdx.x * blockDim.x + threadIdx.x;
    if (i < NE) atomicAdd(&deg[ei[NE + i]], 1);
}

__global__ __launch_bounds__(1024) void k_scan(const int* __restrict__ deg,
        int* __restrict__ rowptr, int* __restrict__ nextp) {
    __shared__ int part[1024];
    const int t = threadIdx.x;
    const int b0 = t * 20;
    const int b1 = min(b0 + 20, NN);
    int s = 0;
    for (int i = b0; i < b1; ++i) s += deg[i];
    part[t] = s;
    __syncthreads();
    for (int off = 1; off < 1024; off <<= 1) {
        int val = (t >= off) ? part[t - off] : 0;
        __syncthreads();
        part[t] += val;
        __syncthreads();
    }
    int run = (t == 0) ? 0 : part[t - 1];
    for (int i = b0; i < b1; ++i) {
        rowptr[i] = run;
        nextp[i] = run;
        run += deg[i];
    }
    if (b1 == NN) rowptr[NN] = run;
}

// ---- scatter: esrc + ea pre-gathered to CSR order (bf16) ----
__global__ void k_scatter(const int* __restrict__ ei, int* __restrict__ nextp,
        int* __restrict__ esrc, ushort_t* __restrict__ eacsr,
        const float* __restrict__ ea) {
    int i = blockIdx.x * blockDim.x + threadIdx.x;
    if (i < NE) {
        int d = ei[NE + i];
        int pos = atomicAdd(&nextp[d], 1);
        esrc[pos] = ei[i];
        const float4* s = (const float4*)&ea[(size_t)i * ED];
        ushort_t* dst = eacsr + (size_t)pos * ED;
        #pragma unroll
        for (int r = 0; r < 4; ++r) {
            float4 f = s[r];
            ushort4 u;
            u.x = f2bf(f.x); u.y = f2bf(f.y); u.z = f2bf(f.z); u.w = f2bf(f.w);
            *(ushort4*)&dst[r * 4] = u;
        }
    }
}

// ---- fused conv: one wave per dst node; 2 edges/iter, DEPTH-2 pipeline ----
// lane: g = lane>>5 (edge slot), j = lane&31 (cols j*4..+3), h = j>>3, w8 = j&7
// kv rows are fp8 e4m3, 256B/row (2 cache lines); lane j reads 8B (4 k + 4 v).
__global__ __launch_bounds__(256) void k_conv(
        const float* __restrict__ q, const unsigned char* __restrict__ kv,
        const ushort_t* __restrict__ eacsr,
        const float* __restrict__ qwe, const float* __restrict__ We,
        const int* __restrict__ rowptr, const int* __restrict__ esrc,
        const int* __restrict__ batch,
        float* __restrict__ hout, float* __restrict__ gsum, int mode) {
    const int wid = (blockIdx.x * blockDim.x + threadIdx.x) >> 6;
    if (wid >= NN) return;
    const int lane = threadIdx.x & 63;
    const int g = lane >> 5;
    const int j = lane & 31;
    const int c0 = j * 4;
    const int h = j >> 3;
    const int w8 = j & 7;
    const int beg = rowptr[wid];
    const int end = rowptr[wid + 1];
    const float4 qq = *(const float4*)&q[(size_t)wid * HC + c0];
    const float2 qw2 = *(const float2*)&qwe[(size_t)wid * 64 + h * 16 + w8 * 2];
    float4 av = make_float4(0.f, 0.f, 0.f, 0.f);
    float2 s2 = make_float2(0.f, 0.f);
    float den = 0.f;

    if (end > beg) {
        const int last = end - 1;
        int s0i = esrc[min(beg + g, last)];
        int s1i = esrc[min(beg + 2 + g, last)];
        int srcA = esrc[min(beg + 4 + g, last)];
        int srcB = esrc[min(beg + 6 + g, last)];
        uint2 kv0 = *(const uint2*)&kv[(size_t)s0i * 256 + j * 8];
        unsigned ea0 = *(const unsigned*)&eacsr[(size_t)min(beg + g, last) * ED + w8 * 2];
        uint2 kv1 = *(const uint2*)&kv[(size_t)s1i * 256 + j * 8];
        unsigned ea1 = *(const unsigned*)&eacsr[(size_t)min(beg + 2 + g, last) * ED + w8 * 2];
        bool act0 = (beg + g) < end;
        bool act1 = (beg + 2 + g) < end;
        const int niter = (end - beg + 1) >> 1;
        for (int i = 0; i < niter; ++i) {
            int srcN = esrc[min(beg + 2 * (i + 4) + g, last)];
            uint2 kv2 = *(const uint2*)&kv[(size_t)srcA * 256 + j * 8];
            unsigned ea2 = *(const unsigned*)&eacsr[(size_t)min(beg + 2 * (i + 2) + g, last) * ED + w8 * 2];
            bool act2 = (beg + 2 * (i + 2) + g) < end;
            v2f k01 = __builtin_amdgcn_cvt_pk_f32_fp8(kv0.x, false);
            v2f k23 = __builtin_amdgcn_cvt_pk_f32_fp8(kv0.x, true);
            v2f v01 = __builtin_amdgcn_cvt_pk_f32_fp8(kv0.y, false);
            v2f v23 = __builtin_amdgcn_cvt_pk_f32_fp8(kv0.y, true);
            float e0 = bf2f(ea0 & 0xffffu), e1 = bf2f(ea0 >> 16);
            float part = qq.x * k01.x + qq.y * k01.y + qq.z * k23.x + qq.w * k23.y
                       + qw2.x * e0 + qw2.y * e1;
            part += __shfl_xor(part, 1);
            part += __shfl_xor(part, 2);
            part += __shfl_xor(part, 4);   // per-head logit (8 lanes/head)
            float p = act0 ? __expf(part * 0.17677669529663687f) : 0.f;
            den += p;
            av.x += p * v01.x; av.y += p * v01.y;
            av.z += p * v23.x; av.w += p * v23.y;
            s2.x += p * e0; s2.y += p * e1;
            kv0 = kv1; ea0 = ea1; act0 = act1;
            kv1 = kv2; ea1 = ea2; act1 = act2;
            srcA = srcB; srcB = srcN;
        }
    }
    den  += __shfl_xor(den, 32);
    av.x += __shfl_xor(av.x, 32); av.y += __shfl_xor(av.y, 32);
    av.z += __shfl_xor(av.z, 32); av.w += __shfl_xor(av.w, 32);
    s2.x += __shfl_xor(s2.x, 32); s2.y += __shfl_xor(s2.y, 32);
    const float inv = 1.f / (den + 1e-16f);
    float4 ew = make_float4(0.f, 0.f, 0.f, 0.f);
    #pragma unroll
    for (int t = 0; t < 8; ++t) {
        float sva = __shfl(s2.x, h * 8 + t, 32);
        float svb = __shfl(s2.y, h * 8 + t, 32);
        float4 wa = *(const float4*)&We[(2 * t) * HC + c0];
        float4 wb = *(const float4*)&We[(2 * t + 1) * HC + c0];
        ew.x += sva * wa.x + svb * wb.x;
        ew.y += sva * wa.y + svb * wb.y;
        ew.z += sva * wa.z + svb * wb.z;
        ew.w += sva * wa.w + svb * wb.w;
    }
    float o[4];
    o[0] = (av.x + ew.x) * inv; o[1] = (av.y + ew.y) * inv;
    o[2] = (av.z + ew.z) * inv; o[3] = (av.w + ew.w) * inv;

    const int b = batch[wid];
    if (mode == 0) {
        #pragma unroll
        for (int c = 0; c < 4; ++c) o[c] = fmaxf(o[c], 0.f);
        if (g == 0)
            *(float4*)&hout[(size_t)wid * HC + c0] =
                make_float4(o[0], o[1], o[2], o[3]);
    }
    #pragma unroll
    for (int c = 0; c < 4; ++c) {
        o[c] += __shfl_xor(o[c], 8);
        o[c] += __shfl_xor(o[c], 16);
    }
    if (lane < 8) {
        #pragma unroll
        for (int c = 0; c < 4; ++c) {
            float pv = 0.25f * o[c];
            if (mode == 1) pv = fmaxf(pv, 0.f);
            atomicAdd(&gsum[b * CD + w8 * 4 + c], pv);
        }
    }
}

// ---- final MLP + log_softmax: one block per graph ----
__global__ __launch_bounds__(128) void k_final(
        const float* __restrict__ gsum, const int* __restrict__ batch,
        const float* __restrict__ W1, const float* __restrict__ b1,
        const float* __restrict__ W2, const float* __restrict__ b2,
        float* __restrict__ out) {
    __shared__ float G[96];
    __shared__ float Y[96];
    __shared__ float Z[10];
    __shared__ int bnd[2];
    const int g = blockIdx.x;
    const int t = threadIdx.x;
    if (t < 2) {
        const int target = g + t;
        int lo = 0, hi = NN;
        while (lo < hi) {
            int mid = (lo + hi) >> 1;
            if (batch[mid] < target) lo = mid + 1; else hi = mid;
        }
        bnd[t] = lo;
    }
    __syncthreads();
    const float cn = fmaxf((float)(bnd[1] - bnd[0]), 1.f);
    if (t < 96) {
        int layer = t / 32, c = t % 32;
        G[t] = gsum[layer * NG * CD + g * CD + c] / cn;
    }
    __syncthreads();
    if (t < 96) {
        float s = b1[t];
        #pragma unroll 4
        for (int d = 0; d < 96; ++d) s += G[d] * W1[d * 96 + t];
        Y[t] = fmaxf(s, 0.f);
    }
    __syncthreads();
    if (t < 10) {
        float s = b2[t];
        #pragma unroll 4
        for (int d = 0; d < 96; ++d) s += Y[d] * W2[d * 10 + t];
        Z[t] = s;
    }
    __syncthreads();
    if (t < 10) {
        float mx = Z[0];
        #pragma unroll
        for (int o = 1; o < 10; ++o) mx = fmaxf(mx, Z[o]);
        float se = 0.f;
        #pragma unroll
        for (int o = 0; o < 10; ++o) se += expf(Z[o] - mx);
        out[g * 10 + t] = Z[t] - (mx + logf(se));
    }
}

extern "C" void kernel_launch(void* const* d_in, const int* in_sizes, int n_in,
                              void* d_out, int out_size, void* d_ws, size_t ws_size,
                              hipStream_t stream) {
    const float* x        = (const float*)d_in[0];
    const float* ea       = (const float*)d_in[1];
    const int*   ei       = (const int*)d_in[2];
    const int*   batch    = (const int*)d_in[3];
    const float* Wq[3] = {(const float*)d_in[4],  (const float*)d_in[8],  (const float*)d_in[12]};
    const float* Wk[3] = {(const float*)d_in[5],  (const float*)d_in[9],  (const float*)d_in[13]};
    const float* Wv[3] = {(const float*)d_in[6],  (const float*)d_in[10], (const float*)d_in[14]};
    const float* We[3] = {(const float*)d_in[7],  (const float*)d_in[11], (const float*)d_in[15]};
    const float* W1 = (const float*)d_in[16];
    const float* b1 = (const float*)d_in[17];
    const float* W2 = (const float*)d_in[18];
    const float* b2 = (const float*)d_in[19];
    float* out = (float*)d_out;

    // workspace layout (all 16B-aligned chunks)
    float* ws = (float*)d_ws;
    float* q      = ws;                      // NN*HC f32
    float* h1     = q + (size_t)NN * HC;     // NN*HC f32
    float* h2     = h1 + (size_t)NN * HC;    // NN*HC f32
    float* qwe    = h2 + (size_t)NN * HC;    // NN*64 f32
    float* gsum   = qwe + (size_t)NN * 64;   // 3*NG*CD
    int* deg      = (int*)(gsum + 3 * NG * CD);  // NN
    int* rowptr   = deg + NN;                // NN+2
    int* nextp    = rowptr + NN + 2;         // NN
    int* esrc     = nextp + NN;              // NE
    unsigned char* kv = (unsigned char*)(esrc + NE);   // NN*256 fp8 bytes
    ushort_t* eacsr = (ushort_t*)(kv + (size_t)NN * 256);  // NE*ED bf16

    hipMemsetAsync(gsum, 0, (3 * NG * CD) * sizeof(float), stream);
    hipMemsetAsync(deg, 0, NN * sizeof(int), stream);

    // CSR build (edge_index shared by all layers)
    k_hist<<<(NE + 255) / 256, 256, 0, stream>>>(ei, deg);
    k_scan<<<1, 1024, 0, stream>>>(deg, rowptr, nextp);
    k_scatter<<<(NE + 255) / 256, 256, 0, stream>>>(ei, nextp, esrc, eacsr, ea);

    const float* conv_in[3] = {x, h1, h2};
    float* conv_out[3] = {h1, h2, nullptr};
    const int CONV_BLOCKS = (NN * 64) / 256;   // one wave per node, 4 waves/block

    for (int l = 0; l < 3; ++l) {
        k_qkv<<<dim3(NN / 32, 3), 256, 0, stream>>>(conv_in[l], Wq[l], Wk[l], Wv[l],
                                                    We[l], q, kv, qwe);
        k_conv<<<CONV_BLOCKS, 256, 0, stream>>>(q, kv, eacsr, qwe, We[l],
                rowptr, esrc, batch,
                conv_out[l], gsum + l * NG * CD, (l < 2) ? 0 : 1);
    }
    k_final<<<NG, 128, 0, stream>>>(gsum, batch, W1, b1, W2, b2, out);
}